// Round 4
// baseline (365.554 us; speedup 1.0000x reference)
//
#include <hip/hip_runtime.h>
#include <math.h>

#define FFT_N 16384
#define MASK (FFT_N - 1)
#define NT 1024
#define RPT 16
#define B_DIM 8
#define H_DIM 256

// b32 pad scheme, measured zero-conflict in R2: one extra float per 32.
#define LDSF (FFT_N + (FFT_N >> 5))   // 16896 floats per component plane
#define IDX(i) ((i) + ((i) >> 5))

__device__ __forceinline__ float2 cmul(float2 a, float2 b) {
    return make_float2(a.x * b.x - a.y * b.y, a.x * b.y + a.y * b.x);
}
__device__ __forceinline__ float2 cadd(float2 a, float2 b) { return make_float2(a.x + b.x, a.y + b.y); }
__device__ __forceinline__ float2 csub(float2 a, float2 b) { return make_float2(a.x - b.x, a.y - b.y); }
__device__ __forceinline__ float2 mulnegi(float2 z) { return make_float2(z.y, -z.x); }   // -i*z
__device__ __forceinline__ float2 mulposi(float2 z) { return make_float2(-z.y, z.x); }   // +i*z

// ---- radix-4 butterflies (algebra correctness-verified through R1..R3 passes) ----
__device__ __forceinline__ void bfly4(float2& a, float2& b, float2& c, float2& d,
                                      float2 w1, float2 w2, float2 w3) {
    float2 apc = cadd(a, c), amc = csub(a, c);
    float2 bpd = cadd(b, d), bmd = csub(b, d);
    float2 nib = mulnegi(bmd);
    a = cadd(apc, bpd);
    b = cmul(csub(apc, bpd), w2);
    c = cmul(cadd(amc, nib), w1);
    d = cmul(csub(amc, nib), w3);
}
__device__ __forceinline__ void bfly4_nw(float2& a, float2& b, float2& c, float2& d) {
    float2 apc = cadd(a, c), amc = csub(a, c);
    float2 bpd = cadd(b, d), bmd = csub(b, d);
    float2 nib = mulnegi(bmd);
    a = cadd(apc, bpd);
    b = csub(apc, bpd);
    c = cadd(amc, nib);
    d = csub(amc, nib);
}
__device__ __forceinline__ void ibfly4(float2& a, float2& b, float2& c, float2& d,
                                       float2 w1t, float2 w2t) {
    float2 w1 = make_float2(w1t.x, -w1t.y);
    float2 w2 = make_float2(w2t.x, -w2t.y);
    float2 bt = cmul(b, w2), dt = cmul(d, w2);
    float2 A = cadd(a, bt), Bb = csub(a, bt);
    float2 C = cadd(c, dt), Dd = csub(c, dt);
    float2 Cw = cmul(C, w1);
    float2 Dw = mulposi(cmul(Dd, w1));
    a = cadd(A, Cw);  c = csub(A, Cw);
    b = cadd(Bb, Dw); d = csub(Bb, Dw);
}
__device__ __forceinline__ void ibfly4_nw(float2& a, float2& b, float2& c, float2& d) {
    float2 A = cadd(a, b), Bb = csub(a, b);
    float2 C = cadd(c, d), Dd = csub(c, d);
    float2 Dw = mulposi(Dd);
    a = cadd(A, C);  c = csub(A, C);
    b = cadd(Bb, Dw); d = csub(Bb, Dw);
}

// ---- register phases: two radix-4 stages on r[16] (verified in R3) ----
template<int P, int ST>
__device__ __forceinline__ void fwd_phase16(float2 r[RPT], int lp, const float2* __restrict__ tw) {
#pragma unroll
    for (int j0 = 0; j0 < 4; ++j0) {
        const int i = (lp + P * j0) * ST;
        bfly4(r[j0], r[j0 + 4], r[j0 + 8], r[j0 + 12],
              tw[i & MASK], tw[(2 * i) & MASK], tw[(3 * i) & MASK]);
    }
    {
        const int i = lp * (ST * 4);
        const float2 w1 = tw[i & MASK], w2 = tw[(2 * i) & MASK], w3 = tw[(3 * i) & MASK];
#pragma unroll
        for (int a = 0; a < 4; ++a)
            bfly4(r[4 * a], r[4 * a + 1], r[4 * a + 2], r[4 * a + 3], w1, w2, w3);
    }
}
template<int P, int ST>
__device__ __forceinline__ void inv_phase16(float2 r[RPT], int lp, const float2* __restrict__ tw) {
    {
        const int i = lp * (ST * 4);
        const float2 w1 = tw[i & MASK], w2 = tw[(2 * i) & MASK];
#pragma unroll
        for (int a = 0; a < 4; ++a)
            ibfly4(r[4 * a], r[4 * a + 1], r[4 * a + 2], r[4 * a + 3], w1, w2);
    }
#pragma unroll
    for (int j0 = 0; j0 < 4; ++j0) {
        const int i = (lp + P * j0) * ST;
        ibfly4(r[j0], r[j0 + 4], r[j0 + 8], r[j0 + 12], tw[i & MASK], tw[(2 * i) & MASK]);
    }
}
__device__ __forceinline__ void fwd_phaseD16(float2 r[RPT]) {
#pragma unroll
    for (int a = 0; a < 4; ++a)
        bfly4_nw(r[4 * a], r[4 * a + 1], r[4 * a + 2], r[4 * a + 3]);
}
__device__ __forceinline__ void inv_phaseD16(float2 r[RPT]) {
#pragma unroll
    for (int a = 0; a < 4; ++a)
        ibfly4_nw(r[4 * a], r[4 * a + 1], r[4 * a + 2], r[4 * a + 3]);
}

// ---- element index owned by thread t, slot j, per phase (verified in R3) ----
#define nA(t, j) ((t) + NT * (j))
#define nB(t, j) ((((t) >> 6) << 10) + ((t) & 63) + 64 * (j))
#define nC(t, j) ((((t) >> 2) << 6) + ((t) & 3) + 4 * (j))
#define nD(t, j) (16 * (t) + (j))

// Exchange both components through separate padded b32 planes (2 barriers).
// All four maps land <=2 lanes/bank under IDX pad (2-way is free, m136).
#define EXCHANGE(NFROM, NTO)                                            \
    do {                                                                \
        _Pragma("unroll") for (int j = 0; j < RPT; ++j) {               \
            const int f = NFROM(t, j);                                  \
            ldsx[IDX(f)] = r[j].x;                                      \
            ldsy[IDX(f)] = r[j].y;                                      \
        }                                                               \
        __syncthreads();                                                \
        _Pragma("unroll") for (int j = 0; j < RPT; ++j) {               \
            const int g = NTO(t, j);                                    \
            r[j].x = ldsx[IDX(g)];                                      \
            r[j].y = ldsy[IDX(g)];                                      \
        }                                                               \
        __syncthreads();                                                \
    } while (0)

__device__ __forceinline__ float ftanh(float x) {
    float e = __expf(2.0f * x);
    return 1.0f - 2.0f * __builtin_amdgcn_rcpf(e + 1.0f);
}

__global__ void twiddle_init(float2* __restrict__ tw) {
    int t = blockIdx.x * blockDim.x + threadIdx.x;
    if (t < FFT_N) {
        float ang = -2.0f * 3.14159265358979323846f * (float)t / (float)FFT_N;
        float sv, cv;
        sincosf(ang, &sv, &cv);
        tw[t] = make_float2(cv, sv);
    }
}

// Forward FFT of (k_h + dh*delta) -> Kf[h] in DIF storage order.
__global__ __launch_bounds__(NT) void kfft_kernel(const float* __restrict__ k,
                                                  const float* __restrict__ D,
                                                  const float2* __restrict__ tw,
                                                  float2* __restrict__ Kf) {
    __shared__ float ldsx[LDSF];
    __shared__ float ldsy[LDSF];
    const int h = blockIdx.x;
    const int t = threadIdx.x;
    const float* krow = k + (size_t)h * FFT_N;
    float2 r[RPT];
#pragma unroll
    for (int j = 0; j < RPT; ++j) r[j] = make_float2(krow[nA(t, j)], 0.f);
    if (t == 0) r[0].x += D[h * (H_DIM + 1)];
    fwd_phase16<NT, 1>(r, t, tw);
    EXCHANGE(nA, nB);
    fwd_phase16<64, 16>(r, t & 63, tw);
    EXCHANGE(nB, nC);
    fwd_phase16<4, 256>(r, t & 3, tw);
    EXCHANGE(nC, nD);
    fwd_phaseD16(r);
    // nD(t,j)=16t+j: each lane owns 16 contiguous float2 -> float4 stores
    float4* out4 = (float4*)(Kf + (size_t)h * FFT_N);
#pragma unroll
    for (int q = 0; q < 8; ++q)
        out4[8 * t + q] = make_float4(r[2 * q].x, r[2 * q].y, r[2 * q + 1].x, r[2 * q + 1].y);
}

// Batch rows (2p,h) and (2p+1,h) packed as z = u0 + i*u1.
__global__ __launch_bounds__(NT) void conv_kernel(const float* __restrict__ u,
                                                  const float2* __restrict__ tw,
                                                  const float2* __restrict__ Kf,
                                                  float* __restrict__ out) {
    __shared__ float ldsx[LDSF];
    __shared__ float ldsy[LDSF];
    // XCD-chunked bijection (1024 blocks, 1024%8==0): blocks sharing h colocate on one XCD
    const int raw = blockIdx.x;
    const int vb = ((raw & 7) << 7) + (raw >> 3);
    const int h = vb >> 2;
    const int p = vb & 3;
    const int t = threadIdx.x;
    const size_t row0 = ((size_t)(2 * p) * H_DIM + h) * FFT_N;
    const size_t row1 = row0 + (size_t)H_DIM * FFT_N;
    const float* u0 = u + row0;
    const float* u1 = u + row1;

    float2 r[RPT];
#pragma unroll
    for (int j = 0; j < RPT; ++j) {
        const int n = nA(t, j);
        r[j] = make_float2(u0[n], u1[n]);
    }

    fwd_phase16<NT, 1>(r, t, tw);
    EXCHANGE(nA, nB);
    fwd_phase16<64, 16>(r, t & 63, tw);
    EXCHANGE(nB, nC);
    fwd_phase16<4, 256>(r, t & 3, tw);
    EXCHANGE(nC, nD);
    fwd_phaseD16(r);

    // pointwise multiply in digit-reversed storage order + 1/N; float4 Kf loads
    {
        const float4* kf4 = (const float4*)(Kf + (size_t)h * FFT_N);
        const float invN = 1.0f / (float)FFT_N;
#pragma unroll
        for (int q = 0; q < 8; ++q) {
            const float4 w = kf4[8 * t + q];
            const float2 z0 = r[2 * q], z1 = r[2 * q + 1];
            r[2 * q]     = make_float2((z0.x * w.x - z0.y * w.y) * invN,
                                       (z0.x * w.y + z0.y * w.x) * invN);
            r[2 * q + 1] = make_float2((z1.x * w.z - z1.y * w.w) * invN,
                                       (z1.x * w.w + z1.y * w.z) * invN);
        }
    }

    inv_phaseD16(r);
    EXCHANGE(nD, nC);
    inv_phase16<4, 256>(r, t & 3, tw);
    EXCHANGE(nC, nB);
    inv_phase16<64, 16>(r, t & 63, tw);
    EXCHANGE(nB, nA);
    inv_phase16<NT, 1>(r, t, tw);

    float* o0 = out + row0;
    float* o1 = out + row1;
#pragma unroll
    for (int j = 0; j < RPT; ++j) {
        const int n = nA(t, j);
        o0[n] = ftanh(r[j].x);
        o1[n] = ftanh(r[j].y);
    }
}

extern "C" void kernel_launch(void* const* d_in, const int* in_sizes, int n_in,
                              void* d_out, int out_size, void* d_ws, size_t ws_size,
                              hipStream_t stream) {
    const float* u = (const float*)d_in[0];   // (B,H,L) f32
    const float* k = (const float*)d_in[1];   // (H,L)   f32
    const float* D = (const float*)d_in[2];   // (H,H)   f32
    float* out = (float*)d_out;

    float2* tw = (float2*)d_ws;               // 16384 float2 = 128 KiB
    float2* Kf = tw + FFT_N;                  // 256*16384 float2 = 32 MiB

    twiddle_init<<<FFT_N / 256, 256, 0, stream>>>(tw);
    kfft_kernel<<<H_DIM, NT, 0, stream>>>(k, D, tw, Kf);
    conv_kernel<<<(B_DIM / 2) * H_DIM, NT, 0, stream>>>(u, tw, Kf, out);
}

// Round 5
// 289.401 us; speedup vs baseline: 1.2631x; 1.2631x over previous
//
#include <hip/hip_runtime.h>
#include <math.h>

#define FFT_N 16384
#define NT 512
#define RPT 32
#define B_DIM 8
#define H_DIM 256

// b32 pad scheme, measured zero-conflict in R2: one extra float per 32.
#define LDSF (FFT_N + (FFT_N >> 5))   // 16896 floats per component plane (66 KiB)
#define IDX(i) ((i) + ((i) >> 5))

__device__ __forceinline__ float2 cmul(float2 a, float2 b) {
    return make_float2(a.x * b.x - a.y * b.y, a.x * b.y + a.y * b.x);
}
__device__ __forceinline__ float2 cadd(float2 a, float2 b) { return make_float2(a.x + b.x, a.y + b.y); }
__device__ __forceinline__ float2 csub(float2 a, float2 b) { return make_float2(a.x - b.x, a.y - b.y); }
__device__ __forceinline__ float2 mulnegi(float2 z) { return make_float2(z.y, -z.x); }   // -i*z
__device__ __forceinline__ float2 mulposi(float2 z) { return make_float2(-z.y, z.x); }   // +i*z

// ---- radix-4 butterflies (algebra verified R1..R4; table twiddles verified R3/R4) ----
__device__ __forceinline__ void bfly4(float2& a, float2& b, float2& c, float2& d,
                                      float2 w1, float2 w2, float2 w3) {
    float2 apc = cadd(a, c), amc = csub(a, c);
    float2 bpd = cadd(b, d), bmd = csub(b, d);
    float2 nib = mulnegi(bmd);
    a = cadd(apc, bpd);
    b = cmul(csub(apc, bpd), w2);
    c = cmul(cadd(amc, nib), w1);
    d = cmul(csub(amc, nib), w3);
}
__device__ __forceinline__ void bfly4_nw(float2& a, float2& b, float2& c, float2& d) {
    float2 apc = cadd(a, c), amc = csub(a, c);
    float2 bpd = cadd(b, d), bmd = csub(b, d);
    float2 nib = mulnegi(bmd);
    a = cadd(apc, bpd);
    b = csub(apc, bpd);
    c = cadd(amc, nib);
    d = csub(amc, nib);
}
__device__ __forceinline__ void ibfly4(float2& a, float2& b, float2& c, float2& d,
                                       float2 w1t, float2 w2t) {
    float2 w1 = make_float2(w1t.x, -w1t.y);
    float2 w2 = make_float2(w2t.x, -w2t.y);
    float2 bt = cmul(b, w2), dt = cmul(d, w2);
    float2 A = cadd(a, bt), Bb = csub(a, bt);
    float2 C = cadd(c, dt), Dd = csub(c, dt);
    float2 Cw = cmul(C, w1);
    float2 Dw = mulposi(cmul(Dd, w1));
    a = cadd(A, Cw);  c = csub(A, Cw);
    b = cadd(Bb, Dw); d = csub(Bb, Dw);
}
__device__ __forceinline__ void ibfly4_nw(float2& a, float2& b, float2& c, float2& d) {
    float2 A = cadd(a, b), Bb = csub(a, b);
    float2 C = cadd(c, d), Dd = csub(c, d);
    float2 Dw = mulposi(Dd);
    a = cadd(A, C);  c = csub(A, C);
    b = cadd(Bb, Dw); d = csub(Bb, Dw);
}

// ---- register phases: two radix-4 stages on r[32] (R2 structure, verified) ----
// Twiddle exponents provably < N for all uses (t < len/4, m<=3) -> no masking.
template<int P, int ST>
__device__ __forceinline__ void fwd_phase32(float2 r[RPT], int lp, const float2* __restrict__ tw) {
#pragma unroll
    for (int j0 = 0; j0 < 8; ++j0) {
        const int i = (lp + P * j0) * ST;
        bfly4(r[j0], r[j0 + 8], r[j0 + 16], r[j0 + 24], tw[i], tw[2 * i], tw[3 * i]);
    }
    // second stage: twiddle depends only on g&1 -> two triples, loaded once
    {
        const int ie = lp * (ST * 4), io = (lp + P) * (ST * 4);
        const float2 we1 = tw[ie], we2 = tw[2 * ie], we3 = tw[3 * ie];
        const float2 wo1 = tw[io], wo2 = tw[2 * io], wo3 = tw[3 * io];
#pragma unroll
        for (int m = 0; m < 8; ++m) {
            const int g = (m >> 1) * 8 + (m & 1);
            if (g & 1) bfly4(r[g], r[g + 2], r[g + 4], r[g + 6], wo1, wo2, wo3);
            else       bfly4(r[g], r[g + 2], r[g + 4], r[g + 6], we1, we2, we3);
        }
    }
}
template<int P, int ST>
__device__ __forceinline__ void inv_phase32(float2 r[RPT], int lp, const float2* __restrict__ tw) {
    {
        const int ie = lp * (ST * 4), io = (lp + P) * (ST * 4);
        const float2 we1 = tw[ie], we2 = tw[2 * ie];
        const float2 wo1 = tw[io], wo2 = tw[2 * io];
#pragma unroll
        for (int m = 0; m < 8; ++m) {
            const int g = (m >> 1) * 8 + (m & 1);
            if (g & 1) ibfly4(r[g], r[g + 2], r[g + 4], r[g + 6], wo1, wo2);
            else       ibfly4(r[g], r[g + 2], r[g + 4], r[g + 6], we1, we2);
        }
    }
#pragma unroll
    for (int j0 = 0; j0 < 8; ++j0) {
        const int i = (lp + P * j0) * ST;
        ibfly4(r[j0], r[j0 + 8], r[j0 + 16], r[j0 + 24], tw[i], tw[2 * i]);
    }
}
__device__ __forceinline__ void fwd_phaseD32(float2 r[RPT]) {
#pragma unroll
    for (int a = 0; a < 8; ++a)
        bfly4_nw(r[4 * a], r[4 * a + 1], r[4 * a + 2], r[4 * a + 3]);
}
__device__ __forceinline__ void inv_phaseD32(float2 r[RPT]) {
#pragma unroll
    for (int a = 0; a < 8; ++a)
        ibfly4_nw(r[4 * a], r[4 * a + 1], r[4 * a + 2], r[4 * a + 3]);
}

// ---- element index maps, NT=512 (verified zero-conflict in R2) ----
#define nA(t, j) ((t) + NT * (j))
#define nB(t, j) ((((t) >> 5) << 10) + ((t) & 31) + 32 * (j))
#define nC(t, j) ((((t) >> 1) << 6) + ((t) & 1) + 2 * (j))
#define nD(t, j) (32 * (t) + (j))

// Two-plane exchange: both components move in one barrier pair (12 barriers total).
// Per-plane patterns identical to R2's measured-zero-conflict accesses.
#define EXCHANGE(NFROM, NTO)                                            \
    do {                                                                \
        _Pragma("unroll") for (int j = 0; j < RPT; ++j) {               \
            const int f = NFROM(t, j);                                  \
            ldsx[IDX(f)] = r[j].x;                                      \
            ldsy[IDX(f)] = r[j].y;                                      \
        }                                                               \
        __syncthreads();                                                \
        _Pragma("unroll") for (int j = 0; j < RPT; ++j) {               \
            const int g = NTO(t, j);                                    \
            r[j].x = ldsx[IDX(g)];                                      \
            r[j].y = ldsy[IDX(g)];                                      \
        }                                                               \
        __syncthreads();                                                \
    } while (0)

__device__ __forceinline__ float ftanh(float x) {
    float e = __expf(2.0f * x);
    return 1.0f - 2.0f * __builtin_amdgcn_rcpf(e + 1.0f);
}

__global__ void twiddle_init(float2* __restrict__ tw) {
    int t = blockIdx.x * blockDim.x + threadIdx.x;
    if (t < FFT_N) {
        float ang = -2.0f * 3.14159265358979323846f * (float)t / (float)FFT_N;
        float sv, cv;
        sincosf(ang, &sv, &cv);
        tw[t] = make_float2(cv, sv);
    }
}

// Forward FFT of (k_h + dh*delta) -> Kf[h] in DIF storage order (D folded: verified R3/R4).
__global__ __launch_bounds__(NT) void kfft_kernel(const float* __restrict__ k,
                                                  const float* __restrict__ D,
                                                  const float2* __restrict__ tw,
                                                  float2* __restrict__ Kf) {
    __shared__ float ldsx[LDSF];
    __shared__ float ldsy[LDSF];
    const int h = blockIdx.x;
    const int t = threadIdx.x;
    const float* krow = k + (size_t)h * FFT_N;
    float2 r[RPT];
#pragma unroll
    for (int j = 0; j < RPT; ++j) r[j] = make_float2(krow[nA(t, j)], 0.f);
    if (t == 0) r[0].x += D[h * (H_DIM + 1)];
    fwd_phase32<NT, 1>(r, t, tw);
    EXCHANGE(nA, nB);
    fwd_phase32<32, 16>(r, t & 31, tw);
    EXCHANGE(nB, nC);
    fwd_phase32<2, 256>(r, t & 1, tw);
    EXCHANGE(nC, nD);
    fwd_phaseD32(r);
    // nD(t,j)=32t+j: each lane owns 32 contiguous float2 -> 16 float4 stores
    float4* out4 = (float4*)(Kf + (size_t)h * FFT_N);
#pragma unroll
    for (int q = 0; q < 16; ++q)
        out4[16 * t + q] = make_float4(r[2 * q].x, r[2 * q].y, r[2 * q + 1].x, r[2 * q + 1].y);
}

// Batch rows (2p,h) and (2p+1,h) packed as z = u0 + i*u1.
__global__ __launch_bounds__(NT) void conv_kernel(const float* __restrict__ u,
                                                  const float2* __restrict__ tw,
                                                  const float2* __restrict__ Kf,
                                                  float* __restrict__ out) {
    __shared__ float ldsx[LDSF];
    __shared__ float ldsy[LDSF];
    // XCD-chunked bijection (1024 blocks, 1024%8==0): blocks sharing h colocate per XCD
    const int raw = blockIdx.x;
    const int vb = ((raw & 7) << 7) + (raw >> 3);
    const int h = vb >> 2;
    const int p = vb & 3;
    const int t = threadIdx.x;
    const size_t row0 = ((size_t)(2 * p) * H_DIM + h) * FFT_N;
    const size_t row1 = row0 + (size_t)H_DIM * FFT_N;
    const float* u0 = u + row0;
    const float* u1 = u + row1;

    // L2-prefetch touches for the Kf row (2048 x 64B lines, 4 per thread),
    // issued now, sunk (and thus waited) just before the pointwise step.
    const float* kfw = (const float*)(Kf + (size_t)h * FFT_N);
    const float tch0 = kfw[16 * t];
    const float tch1 = kfw[16 * (t + 512)];
    const float tch2 = kfw[16 * (t + 1024)];
    const float tch3 = kfw[16 * (t + 1536)];

    float2 r[RPT];
#pragma unroll
    for (int j = 0; j < RPT; ++j) {
        const int n = nA(t, j);
        r[j] = make_float2(u0[n], u1[n]);
    }

    fwd_phase32<NT, 1>(r, t, tw);
    EXCHANGE(nA, nB);
    fwd_phase32<32, 16>(r, t & 31, tw);
    EXCHANGE(nB, nC);
    fwd_phase32<2, 256>(r, t & 1, tw);
    EXCHANGE(nC, nD);
    fwd_phaseD32(r);

    // keep prefetch loads live (no DCE), then pointwise multiply (L2-hot Kf)
    asm volatile("" :: "v"(tch0), "v"(tch1), "v"(tch2), "v"(tch3));
    {
        const float4* kf4 = (const float4*)(Kf + (size_t)h * FFT_N);
        const float invN = 1.0f / (float)FFT_N;
#pragma unroll
        for (int q = 0; q < 16; ++q) {
            const float4 w = kf4[16 * t + q];
            const float2 z0 = r[2 * q], z1 = r[2 * q + 1];
            r[2 * q]     = make_float2((z0.x * w.x - z0.y * w.y) * invN,
                                       (z0.x * w.y + z0.y * w.x) * invN);
            r[2 * q + 1] = make_float2((z1.x * w.z - z1.y * w.w) * invN,
                                       (z1.x * w.w + z1.y * w.z) * invN);
        }
    }

    inv_phaseD32(r);
    EXCHANGE(nD, nC);
    inv_phase32<2, 256>(r, t & 1, tw);
    EXCHANGE(nC, nB);
    inv_phase32<32, 16>(r, t & 31, tw);
    EXCHANGE(nB, nA);
    inv_phase32<NT, 1>(r, t, tw);

    float* o0 = out + row0;
    float* o1 = out + row1;
#pragma unroll
    for (int j = 0; j < RPT; ++j) {
        const int n = nA(t, j);
        o0[n] = ftanh(r[j].x);
        o1[n] = ftanh(r[j].y);
    }
}

extern "C" void kernel_launch(void* const* d_in, const int* in_sizes, int n_in,
                              void* d_out, int out_size, void* d_ws, size_t ws_size,
                              hipStream_t stream) {
    const float* u = (const float*)d_in[0];   // (B,H,L) f32
    const float* k = (const float*)d_in[1];   // (H,L)   f32
    const float* D = (const float*)d_in[2];   // (H,H)   f32
    float* out = (float*)d_out;

    float2* tw = (float2*)d_ws;               // 16384 float2 = 128 KiB
    float2* Kf = tw + FFT_N;                  // 256*16384 float2 = 32 MiB

    twiddle_init<<<FFT_N / 256, 256, 0, stream>>>(tw);
    kfft_kernel<<<H_DIM, NT, 0, stream>>>(k, D, tw, Kf);
    conv_kernel<<<(B_DIM / 2) * H_DIM, NT, 0, stream>>>(u, tw, Kf, out);
}